// Round 1
// baseline (9676.817 us; speedup 1.0000x reference)
//
#include <hip/hip_runtime.h>

typedef __attribute__((ext_vector_type(8))) short short8;
typedef __attribute__((ext_vector_type(4))) float floatx4;

#define DEV __device__ __forceinline__

constexpr int B_ = 128, T_ = 256, D_ = 512, L_ = 1024;
constexpr int BL_ = B_ * L_;

// ---- workspace byte offsets ----
constexpr size_t OFF_PREZ = 0;                                  // fp16 [T][B][L]
constexpr size_t OFF_PRER = OFF_PREZ + (size_t)T_ * B_ * L_ * 2;
constexpr size_t OFF_WH   = OFF_PRER + (size_t)T_ * B_ * L_ * 2; // bf16 [3][1024][1024] (h-part of W)
constexpr size_t OFF_WX   = OFF_WH + (size_t)3 * L_ * 1024 * 2;  // bf16 [3][1024][512]  (x-part of W)
constexpr size_t OFF_XB   = OFF_WX + (size_t)3 * L_ * 512 * 2;   // bf16 [B][T][D]
constexpr size_t OFF_HB   = OFF_XB + (size_t)B_ * T_ * D_ * 2;   // bf16 [B][L]  current h
constexpr size_t OFF_RH   = OFF_HB + (size_t)B_ * L_ * 2;        // bf16 [B][L]  r*h
constexpr size_t OFF_Z    = OFF_RH + (size_t)B_ * L_ * 2;        // f32  [B][L]  z gate
constexpr size_t OFF_CTR  = OFF_Z + (size_t)B_ * L_ * 4;         // barrier counters (8 KB zone)

DEV float bf2f(unsigned short u) { unsigned v = ((unsigned)u) << 16; return __uint_as_float(v); }
DEV unsigned short f2bf(float f) {
  unsigned u = __float_as_uint(f);
  u += 0x7fffu + ((u >> 16) & 1u);   // RNE
  return (unsigned short)(u >> 16);
}
DEV unsigned short f2h(float f) { _Float16 h = (_Float16)f; return __builtin_bit_cast(unsigned short, h); }
DEV float h2f(unsigned short u) { _Float16 h = __builtin_bit_cast(_Float16, u); return (float)h; }
DEV float sigmoidf_(float x) { return 1.0f / (1.0f + __expf(-x)); }
DEV float tanhf_(float x) {
  float a = fabsf(x);
  float e = __expf(-2.0f * a);
  float t = (1.0f - e) / (1.0f + e);
  return copysignf(t, x);
}

DEV void gld_lds16(const void* g, void* l) {
  __builtin_amdgcn_global_load_lds(
      (const __attribute__((address_space(1))) unsigned int*)g,
      (__attribute__((address_space(3))) unsigned int*)l, 16, 0, 0);
}

// Two-level grid barrier: 16 groups of 16 blocks. Cumulative counters (no reset).
// ctr[0] = root; group g counter at ctr + 64 + g*64 (256B apart).
DEV void grid_barrier(unsigned* ctr, int blk, unsigned barph) {
  __syncthreads();
  if (threadIdx.x == 0) {
    unsigned* grp = ctr + 64 + (unsigned)(blk >> 4) * 64;
    unsigned old = __hip_atomic_fetch_add(grp, 1u, __ATOMIC_ACQ_REL, __HIP_MEMORY_SCOPE_AGENT);
    if ((old & 15u) == 15u) {
      __hip_atomic_fetch_add(ctr, 1u, __ATOMIC_ACQ_REL, __HIP_MEMORY_SCOPE_AGENT);
    }
    while (__hip_atomic_load(ctr, __ATOMIC_RELAXED, __HIP_MEMORY_SCOPE_AGENT) < barph * 16u)
      __builtin_amdgcn_s_sleep(2);
    __threadfence();  // agent acquire: buffer_inv so remote L2 writes become visible
  }
  __syncthreads();
}

// ---------------- conversion kernels ----------------
__global__ __launch_bounds__(256) void k_conv_x(const float* __restrict__ x,
                                                unsigned short* __restrict__ xb) {
  size_t i = ((size_t)blockIdx.x * 256 + threadIdx.x) * 8;
  float4 f0 = *(const float4*)(x + i);
  float4 f1 = *(const float4*)(x + i + 4);
  short8 o;
  o[0] = (short)f2bf(f0.x); o[1] = (short)f2bf(f0.y); o[2] = (short)f2bf(f0.z); o[3] = (short)f2bf(f0.w);
  o[4] = (short)f2bf(f1.x); o[5] = (short)f2bf(f1.y); o[6] = (short)f2bf(f1.z); o[7] = (short)f2bf(f1.w);
  *(short8*)&xb[i] = o;
}

__global__ __launch_bounds__(256) void k_conv_w(const float* __restrict__ Wz,
                                                const float* __restrict__ Wr,
                                                const float* __restrict__ Wi,
                                                unsigned short* __restrict__ wx,
                                                unsigned short* __restrict__ wh) {
  int idx = blockIdx.x * 256 + threadIdx.x;       // 0 .. 589823 ; 8 elems each
  int g = idx / 196608;                            // 1024 rows * 192 chunks
  int rem = idx - g * 196608;
  int n = rem / 192;
  int c = rem - n * 192;
  int k = c * 8;
  const float* W = (g == 0) ? Wz : ((g == 1) ? Wr : Wi);
  const float* src = W + (size_t)n * 1536 + k;
  short8 o;
#pragma unroll
  for (int u = 0; u < 8; ++u) o[u] = (short)f2bf(src[u]);
  if (k < 512)
    *(short8*)&wx[((size_t)g * 1024 + n) * 512 + k] = o;
  else
    *(short8*)&wh[((size_t)g * 1024 + n) * 1024 + (k - 512)] = o;
}

// ---------------- x-part pre-activation GEMM ----------------
// C[m][n] = sum_k xb[m][k] * wx[n][k],  m = b*256+t over 32768, n over 3072 (3 gates)
// 128x128 tile, BK=64, 4 waves in 2x2, 16 MFMA tiles/wave.
__global__ __launch_bounds__(256) void k_pre_gemm(const unsigned short* __restrict__ xb,
                                                  const unsigned short* __restrict__ wx,
                                                  unsigned short* __restrict__ preZ,
                                                  unsigned short* __restrict__ preR,
                                                  float* __restrict__ outI,
                                                  const float* __restrict__ bz,
                                                  const float* __restrict__ br,
                                                  const float* __restrict__ bi) {
  __shared__ __align__(16) unsigned short As[128 * 64];
  __shared__ __align__(16) unsigned short Bs[128 * 64];
  const int tid = threadIdx.x;
  const int wave = tid >> 6, lane = tid & 63;
  const int m0 = blockIdx.x * 128;
  const int n0g = blockIdx.y * 128;          // 0..3071, gate-uniform per block
  const int g = n0g >> 10;
  const int n0 = n0g & 1023;
  const unsigned short* wg = wx + (size_t)g * 1024 * 512;
  const int wm = (wave >> 1) * 64, wn = (wave & 1) * 64;

  floatx4 acc[4][4];
#pragma unroll
  for (int i = 0; i < 4; ++i)
#pragma unroll
    for (int j = 0; j < 4; ++j) acc[i][j] = (floatx4){0.f, 0.f, 0.f, 0.f};

  for (int ko = 0; ko < 8; ++ko) {
    const int k0 = ko * 64;
#pragma unroll
    for (int j = 0; j < 4; ++j) {
      int rowbase = (wave * 4 + j) * 8;
      int row = rowbase + (lane >> 3);
      int clog = (lane & 7) ^ (row & 7);               // XOR swizzle (8 chunks of 16B per row)
      gld_lds16(xb + (size_t)(m0 + row) * 512 + k0 + clog * 8, &As[rowbase * 64]);
      gld_lds16(wg + (size_t)(n0 + row) * 512 + k0 + clog * 8, &Bs[rowbase * 64]);
    }
    __syncthreads();
#pragma unroll
    for (int ks = 0; ks < 2; ++ks) {
      short8 a[4], b[4];
      int cl = ks * 4 + (lane >> 4);
#pragma unroll
      for (int i = 0; i < 4; ++i) {
        int r = wm + i * 16 + (lane & 15);
        a[i] = *(const short8*)&As[r * 64 + ((cl ^ (r & 7)) * 8)];
      }
#pragma unroll
      for (int j = 0; j < 4; ++j) {
        int r = wn + j * 16 + (lane & 15);
        b[j] = *(const short8*)&Bs[r * 64 + ((cl ^ (r & 7)) * 8)];
      }
#pragma unroll
      for (int i = 0; i < 4; ++i)
#pragma unroll
        for (int j = 0; j < 4; ++j)
          acc[i][j] = __builtin_amdgcn_mfma_f32_16x16x32_bf16(a[i], b[j], acc[i][j], 0, 0, 0);
    }
    __syncthreads();
  }

  const float* bias = (g == 0) ? bz : ((g == 1) ? br : bi);
#pragma unroll
  for (int i = 0; i < 4; ++i)
#pragma unroll
    for (int j = 0; j < 4; ++j) {
      int ncol = n0 + wn + j * 16 + (lane & 15);
      float bv = bias[ncol];
#pragma unroll
      for (int reg = 0; reg < 4; ++reg) {
        int m = m0 + wm + i * 16 + (lane >> 4) * 4 + reg;
        int bidx = m >> 8, t = m & 255;                // m = b*256 + t
        size_t idx = ((size_t)(t * B_ + bidx) << 10) + ncol;
        float v = acc[i][j][reg] + bv;
        if (g == 0)      preZ[idx] = f2h(v);
        else if (g == 1) preR[idx] = f2h(v);
        else             outI[idx] = v;                // pre_i parked in d_out
      }
    }
}

// ---------------- persistent recurrent kernel ----------------
// 256 blocks, 1/CU (LDS 149.5KB). Phase A: a_{z,r} = h @ W{z,r}_h^T (32x32 tile each).
// Phase B: i = tanh(pre_i + (r.h) @ Wi_h^T) (16x32 tile), h update. 2 grid barriers/step.
__global__ __launch_bounds__(256, 1) void k_gru(const unsigned short* __restrict__ wh,
                                                const unsigned short* __restrict__ preZ,
                                                const unsigned short* __restrict__ preR,
                                                unsigned short* __restrict__ hb,
                                                unsigned short* __restrict__ rh,
                                                float* __restrict__ zbuf,
                                                float* __restrict__ out,
                                                unsigned* __restrict__ ctr) {
  __shared__ __align__(16) unsigned short WA[32 * 1024];  // 64 KB: z or r rows (phase A)
  __shared__ __align__(16) unsigned short WB[32 * 1024];  // 64 KB: Wi rows (phase B)
  __shared__ __align__(16) unsigned short Hs[8192];       // 16 KB staging
  __shared__ __align__(16) float red[512];                //  2 KB K-split reduce
  const int tid = threadIdx.x, wave = tid >> 6, lane = tid & 63;
  const int p = blockIdx.x;
  // phase A tile: 32 rows(b) x 32 cols over N=2048 (z|r)
  const int am0 = (p >> 6) * 32;
  const int an0 = (p & 63) * 32;
  const int agate = (an0 < 1024) ? 0 : 1;
  const int an0g = an0 & 1023;
  // phase B tile: 16 rows(b) x 32 cols over N=1024
  const int bm0 = (p >> 5) * 16;
  const int bn0 = (p & 31) * 32;

  // one-time swizzled weight load into LDS (stays resident for all 256 steps)
  {
    const unsigned short* wa = wh + (size_t)agate * 1024 * 1024 + (size_t)an0g * 1024;
    const unsigned short* wb = wh + (size_t)2 * 1024 * 1024 + (size_t)bn0 * 1024;
    for (int idx = tid; idx < 32 * 128; idx += 256) {   // 32 rows x 128 chunks(16B)
      int row = idx >> 7, cl = idx & 127;
      int cp = cl ^ (row & 7);
      *(short8*)&WA[row * 1024 + cp * 8] = *(const short8*)&wa[(size_t)row * 1024 + cl * 8];
      *(short8*)&WB[row * 1024 + cp * 8] = *(const short8*)&wb[(size_t)row * 1024 + cl * 8];
    }
  }
  __syncthreads();

  unsigned barph = 0;
  const int msub = wave >> 1, nsub = wave & 1;

  for (int t = 0; t < T_; ++t) {
    // ---------- Phase A ----------
    floatx4 acc = (floatx4){0.f, 0.f, 0.f, 0.f};
    for (int kq = 0; kq < 4; ++kq) {                    // K quarters of 256
#pragma unroll
      for (int j = 0; j < 4; ++j) {                     // stage 32 rows x 256k (16 KB)
        int rowbase = wave * 8 + j * 2;
        int row = rowbase + (lane >> 5);
        int cl = (lane & 31) ^ (row & 7);
        gld_lds16(hb + (size_t)(am0 + row) * 1024 + kq * 256 + cl * 8, &Hs[rowbase * 256]);
      }
      __syncthreads();
#pragma unroll
      for (int ks = 0; ks < 8; ++ks) {
        int ra = msub * 16 + (lane & 15);
        int cla = ks * 4 + (lane >> 4);                 // 32 chunks/row
        short8 a = *(const short8*)&Hs[ra * 256 + ((cla ^ (ra & 7)) * 8)];
        int rb = nsub * 16 + (lane & 15);
        int clb = kq * 32 + ks * 4 + (lane >> 4);       // 128 chunks/row
        short8 b = *(const short8*)&WA[rb * 1024 + ((clb ^ (rb & 7)) * 8)];
        acc = __builtin_amdgcn_mfma_f32_16x16x32_bf16(a, b, acc, 0, 0, 0);
      }
      __syncthreads();
    }
    {
      int ncol = an0 + nsub * 16 + (lane & 15);
      int nl = ncol & 1023;
      const unsigned short* pz = ((agate == 0) ? preZ : preR) + (size_t)t * BL_;
#pragma unroll
      for (int reg = 0; reg < 4; ++reg) {
        int brow = am0 + msub * 16 + (lane >> 4) * 4 + reg;
        float v = acc[reg] + h2f(pz[(size_t)brow * 1024 + nl]);
        float s = sigmoidf_(v);
        if (agate == 0) {
          zbuf[brow * 1024 + nl] = s;
        } else {
          float hp = (t > 0) ? out[(size_t)(t - 1) * BL_ + (size_t)brow * 1024 + nl] : 0.f;
          rh[brow * 1024 + nl] = f2bf(s * hp);
        }
      }
    }
    ++barph;
    grid_barrier(ctr, p, barph);

    // ---------- Phase B ----------
    floatx4 acc2 = (floatx4){0.f, 0.f, 0.f, 0.f};
    const int q = wave >> 1, nsb = wave & 1;            // K-quarter, n-subtile
    for (int half = 0; half < 2; ++half) {
#pragma unroll
      for (int j = 0; j < 4; ++j) {                     // stage 16 rows x 512k (16 KB)
        int row = wave * 4 + j;
        int cl = lane ^ (row & 7);                      // 64 chunks/row
        gld_lds16(rh + (size_t)(bm0 + row) * 1024 + half * 512 + cl * 8, &Hs[row * 512]);
      }
      __syncthreads();
#pragma unroll
      for (int ks = 0; ks < 8; ++ks) {
        int ra = lane & 15;
        int cla = q * 32 + ks * 4 + (lane >> 4);        // chunk within staged half
        short8 a = *(const short8*)&Hs[ra * 512 + ((cla ^ (ra & 7)) * 8)];
        int rb = nsb * 16 + (lane & 15);
        int clb = half * 64 + cla;
        short8 b = *(const short8*)&WB[rb * 1024 + ((clb ^ (rb & 7)) * 8)];
        acc2 = __builtin_amdgcn_mfma_f32_16x16x32_bf16(a, b, acc2, 0, 0, 0);
      }
      __syncthreads();
    }
    // waves (0,2) and (1,3) each cover full K for one 16x16 tile: reduce pairs
    if (wave >= 2) *(floatx4*)&red[(wave - 2) * 256 + lane * 4] = acc2;
    __syncthreads();
    if (wave < 2) {
      floatx4 r4 = *(const floatx4*)&red[wave * 256 + lane * 4];
      acc2 = acc2 + r4;
      int n = bn0 + nsb * 16 + (lane & 15);
#pragma unroll
      for (int reg = 0; reg < 4; ++reg) {
        int m = bm0 + (lane >> 4) * 4 + reg;
        size_t idx = (size_t)t * BL_ + (size_t)m * 1024 + n;
        float ip = acc2[reg] + out[idx];                // pre_i parked here
        float iv = tanhf_(ip);
        float z = zbuf[m * 1024 + n];
        float hp = (t > 0) ? out[idx - BL_] : 0.f;
        float h = (1.f - z) * hp + z * iv;
        out[idx] = h;
        hb[m * 1024 + n] = f2bf(h);
      }
    }
    if (t + 1 < T_) {
      ++barph;
      grid_barrier(ctr, p, barph);
    }
  }
}

extern "C" void kernel_launch(void* const* d_in, const int* in_sizes, int n_in,
                              void* d_out, int out_size, void* d_ws, size_t ws_size,
                              hipStream_t stream) {
  const float* x  = (const float*)d_in[0];
  const float* Wz = (const float*)d_in[1];
  const float* bz = (const float*)d_in[2];
  const float* Wr = (const float*)d_in[3];
  const float* br = (const float*)d_in[4];
  const float* Wi = (const float*)d_in[5];
  const float* bi = (const float*)d_in[6];
  float* out = (float*)d_out;
  char* wsb = (char*)d_ws;

  unsigned short* preZ = (unsigned short*)(wsb + OFF_PREZ);
  unsigned short* preR = (unsigned short*)(wsb + OFF_PRER);
  unsigned short* wh   = (unsigned short*)(wsb + OFF_WH);
  unsigned short* wx   = (unsigned short*)(wsb + OFF_WX);
  unsigned short* xb   = (unsigned short*)(wsb + OFF_XB);
  unsigned short* hb   = (unsigned short*)(wsb + OFF_HB);
  unsigned short* rh   = (unsigned short*)(wsb + OFF_RH);
  float* zbuf          = (float*)(wsb + OFF_Z);
  unsigned* ctr        = (unsigned*)(wsb + OFF_CTR);

  hipMemsetAsync(wsb + OFF_HB, 0, (size_t)B_ * L_ * 2, stream);   // h0 = 0
  hipMemsetAsync(wsb + OFF_CTR, 0, 8192, stream);                 // barrier counters

  k_conv_x<<<8192, 256, 0, stream>>>(x, xb);
  k_conv_w<<<2304, 256, 0, stream>>>(Wz, Wr, Wi, wx, wh);
  k_pre_gemm<<<dim3(256, 24), 256, 0, stream>>>(xb, wx, preZ, preR, out, bz, br, bi);
  k_gru<<<256, 256, 0, stream>>>(wh, preZ, preR, hb, rh, zbuf, out, ctr);
}

// Round 2
// 3002.311 us; speedup vs baseline: 3.2231x; 3.2231x over previous
//
#include <hip/hip_runtime.h>

typedef __attribute__((ext_vector_type(8))) short short8;
typedef __attribute__((ext_vector_type(4))) float floatx4;
typedef unsigned long long u64;
typedef unsigned short ushort;

#define DEV __device__ __forceinline__

constexpr int B_ = 128, T_ = 256, D_ = 512, L_ = 1024;
constexpr int BL_ = B_ * L_;

// ---- workspace byte offsets ----
constexpr size_t OFF_PREZ = 0;                                  // fp16 [T][B][L]
constexpr size_t OFF_PRER = OFF_PREZ + (size_t)T_ * B_ * L_ * 2;
constexpr size_t OFF_WH   = OFF_PRER + (size_t)T_ * B_ * L_ * 2; // bf16 [3][1024][1024]
constexpr size_t OFF_WX   = OFF_WH + (size_t)3 * L_ * 1024 * 2;  // bf16 [3][1024][512]
constexpr size_t OFF_XB   = OFF_WX + (size_t)3 * L_ * 512 * 2;   // bf16 [B][T][D]
constexpr size_t OFF_HB   = OFF_XB + (size_t)B_ * T_ * D_ * 2;   // bf16 [B][L] current h
constexpr size_t OFF_RH   = OFF_HB + (size_t)B_ * L_ * 2;        // bf16 [B][L] r*h
constexpr size_t OFF_Z    = OFF_RH + (size_t)B_ * L_ * 2;        // f32  [B][L] z gate
constexpr size_t OFF_CTR  = OFF_Z + (size_t)B_ * L_ * 4;         // barrier counters (16 KB)

DEV unsigned short f2bf(float f) {
  unsigned u = __float_as_uint(f);
  u += 0x7fffu + ((u >> 16) & 1u);   // RNE
  return (unsigned short)(u >> 16);
}
DEV unsigned short f2h(float f) { _Float16 h = (_Float16)f; return __builtin_bit_cast(unsigned short, h); }
DEV float h2f(unsigned short u) { _Float16 h = __builtin_bit_cast(_Float16, u); return (float)h; }
DEV float sigmoidf_(float x) { return 1.0f / (1.0f + __expf(-x)); }
DEV float tanhf_(float x) {
  float a = fabsf(x);
  float e = __expf(-2.0f * a);
  float t = (1.0f - e) / (1.0f + e);
  return copysignf(t, x);
}

// ---- coherent (agent-scope, relaxed: no cache-maintenance) access helpers ----
DEV u64 cload64(const void* p) {
  return __hip_atomic_load((const u64*)p, __ATOMIC_RELAXED, __HIP_MEMORY_SCOPE_AGENT);
}
DEV void cstore64(void* p, u64 v) {
  __hip_atomic_store((u64*)p, v, __ATOMIC_RELAXED, __HIP_MEMORY_SCOPE_AGENT);
}
DEV u64 pack2f(float a, float b) { float2 t; t.x = a; t.y = b; return __builtin_bit_cast(u64, t); }
DEV float2 unpack2f(u64 v) { return __builtin_bit_cast(float2, v); }

DEV void gld_lds16(const void* g, void* l) {
  __builtin_amdgcn_global_load_lds(
      (const __attribute__((address_space(1))) unsigned int*)g,
      (__attribute__((address_space(3))) unsigned int*)l, 16, 0, 0);
}

// ---- relaxed two-level grid barrier (NO fences, NO L2 flush) ----
// layout in ctr: [0]=root (cumulative, +16/interval); [64+g*64]=group arrive; [2048+g*64]=group go
DEV void bar_arrive(unsigned* ctr, int p, unsigned iv) {
  // caller guarantees __syncthreads() immediately before (drains vmcnt for all waves)
  if (threadIdx.x == 0) {
    unsigned* grp = ctr + 64 + (unsigned)(p >> 4) * 64;
    unsigned old = __hip_atomic_fetch_add(grp, 1u, __ATOMIC_RELAXED, __HIP_MEMORY_SCOPE_AGENT);
    if (old == iv * 16u - 1u)
      __hip_atomic_fetch_add(ctr, 1u, __ATOMIC_RELAXED, __HIP_MEMORY_SCOPE_AGENT);
  }
}
DEV void bar_wait(unsigned* ctr, int p, unsigned iv) {
  if (threadIdx.x == 0) {
    unsigned g = (unsigned)(p >> 4);
    unsigned* go = ctr + 2048 + g * 64;
    if ((p & 15) == 0) {
      while (__hip_atomic_load(ctr, __ATOMIC_RELAXED, __HIP_MEMORY_SCOPE_AGENT) < iv * 16u)
        __builtin_amdgcn_s_sleep(1);
      __hip_atomic_store(go, iv, __ATOMIC_RELAXED, __HIP_MEMORY_SCOPE_AGENT);
    } else {
      while (__hip_atomic_load(go, __ATOMIC_RELAXED, __HIP_MEMORY_SCOPE_AGENT) < iv)
        __builtin_amdgcn_s_sleep(1);
    }
  }
  __syncthreads();
}

// ---------------- conversion kernels (unchanged, verified) ----------------
__global__ __launch_bounds__(256) void k_conv_x(const float* __restrict__ x,
                                                unsigned short* __restrict__ xb) {
  size_t i = ((size_t)blockIdx.x * 256 + threadIdx.x) * 8;
  float4 f0 = *(const float4*)(x + i);
  float4 f1 = *(const float4*)(x + i + 4);
  short8 o;
  o[0] = (short)f2bf(f0.x); o[1] = (short)f2bf(f0.y); o[2] = (short)f2bf(f0.z); o[3] = (short)f2bf(f0.w);
  o[4] = (short)f2bf(f1.x); o[5] = (short)f2bf(f1.y); o[6] = (short)f2bf(f1.z); o[7] = (short)f2bf(f1.w);
  *(short8*)&xb[i] = o;
}

__global__ __launch_bounds__(256) void k_conv_w(const float* __restrict__ Wz,
                                                const float* __restrict__ Wr,
                                                const float* __restrict__ Wi,
                                                unsigned short* __restrict__ wx,
                                                unsigned short* __restrict__ wh) {
  int idx = blockIdx.x * 256 + threadIdx.x;
  int g = idx / 196608;
  int rem = idx - g * 196608;
  int n = rem / 192;
  int c = rem - n * 192;
  int k = c * 8;
  const float* W = (g == 0) ? Wz : ((g == 1) ? Wr : Wi);
  const float* src = W + (size_t)n * 1536 + k;
  short8 o;
#pragma unroll
  for (int u = 0; u < 8; ++u) o[u] = (short)f2bf(src[u]);
  if (k < 512)
    *(short8*)&wx[((size_t)g * 1024 + n) * 512 + k] = o;
  else
    *(short8*)&wh[((size_t)g * 1024 + n) * 1024 + (k - 512)] = o;
}

// ---------------- x-part pre-activation GEMM (unchanged, verified) ----------------
__global__ __launch_bounds__(256) void k_pre_gemm(const unsigned short* __restrict__ xb,
                                                  const unsigned short* __restrict__ wx,
                                                  unsigned short* __restrict__ preZ,
                                                  unsigned short* __restrict__ preR,
                                                  float* __restrict__ outI,
                                                  const float* __restrict__ bz,
                                                  const float* __restrict__ br,
                                                  const float* __restrict__ bi) {
  __shared__ __align__(16) unsigned short As[128 * 64];
  __shared__ __align__(16) unsigned short Bs[128 * 64];
  const int tid = threadIdx.x;
  const int wave = tid >> 6, lane = tid & 63;
  const int m0 = blockIdx.x * 128;
  const int n0g = blockIdx.y * 128;
  const int g = n0g >> 10;
  const int n0 = n0g & 1023;
  const unsigned short* wg = wx + (size_t)g * 1024 * 512;
  const int wm = (wave >> 1) * 64, wn = (wave & 1) * 64;

  floatx4 acc[4][4];
#pragma unroll
  for (int i = 0; i < 4; ++i)
#pragma unroll
    for (int j = 0; j < 4; ++j) acc[i][j] = (floatx4){0.f, 0.f, 0.f, 0.f};

  for (int ko = 0; ko < 8; ++ko) {
    const int k0 = ko * 64;
#pragma unroll
    for (int j = 0; j < 4; ++j) {
      int rowbase = (wave * 4 + j) * 8;
      int row = rowbase + (lane >> 3);
      int clog = (lane & 7) ^ (row & 7);
      gld_lds16(xb + (size_t)(m0 + row) * 512 + k0 + clog * 8, &As[rowbase * 64]);
      gld_lds16(wg + (size_t)(n0 + row) * 512 + k0 + clog * 8, &Bs[rowbase * 64]);
    }
    __syncthreads();
#pragma unroll
    for (int ks = 0; ks < 2; ++ks) {
      short8 a[4], b[4];
      int cl = ks * 4 + (lane >> 4);
#pragma unroll
      for (int i = 0; i < 4; ++i) {
        int r = wm + i * 16 + (lane & 15);
        a[i] = *(const short8*)&As[r * 64 + ((cl ^ (r & 7)) * 8)];
      }
#pragma unroll
      for (int j = 0; j < 4; ++j) {
        int r = wn + j * 16 + (lane & 15);
        b[j] = *(const short8*)&Bs[r * 64 + ((cl ^ (r & 7)) * 8)];
      }
#pragma unroll
      for (int i = 0; i < 4; ++i)
#pragma unroll
        for (int j = 0; j < 4; ++j)
          acc[i][j] = __builtin_amdgcn_mfma_f32_16x16x32_bf16(a[i], b[j], acc[i][j], 0, 0, 0);
    }
    __syncthreads();
  }

  const float* bias = (g == 0) ? bz : ((g == 1) ? br : bi);
#pragma unroll
  for (int i = 0; i < 4; ++i)
#pragma unroll
    for (int j = 0; j < 4; ++j) {
      int ncol = n0 + wn + j * 16 + (lane & 15);
      float bv = bias[ncol];
#pragma unroll
      for (int reg = 0; reg < 4; ++reg) {
        int m = m0 + wm + i * 16 + (lane >> 4) * 4 + reg;
        int bidx = m >> 8, t = m & 255;
        size_t idx = ((size_t)(t * B_ + bidx) << 10) + ncol;
        float v = acc[i][j][reg] + bv;
        if (g == 0)      preZ[idx] = f2h(v);
        else if (g == 1) preR[idx] = f2h(v);
        else             outI[idx] = v;                // pre_i parked in d_out
      }
    }
}

// ---------------- persistent recurrent kernel ----------------
// 256 blocks, 1/CU. Weights LDS-resident. All cross-block traffic via agent-relaxed
// (sc-flagged) loads/stores -> memory-side L3; barriers are fence-free.
// Phase A tile: 32 b-rows x 32 cols of [z|r] (N=2048). Phase B tile: 32 b-rows x 16 cols of i.
__global__ __launch_bounds__(256, 1) void k_gru(const unsigned short* __restrict__ wh,
                                                const unsigned short* __restrict__ preZ,
                                                const unsigned short* __restrict__ preR,
                                                unsigned short* __restrict__ hb,
                                                unsigned short* __restrict__ rh,
                                                float* __restrict__ zbuf,
                                                float* __restrict__ out,
                                                unsigned* __restrict__ ctr) {
  __shared__ __align__(16) unsigned short WA[32 * 1024];  // 64 KB
  __shared__ __align__(16) unsigned short WB[16 * 1024];  // 32 KB
  __shared__ __align__(16) unsigned short Hs[32 * 512];   // 32 KB staging (K-half)
  __shared__ __align__(16) float red[512];                //  2 KB

  const int tid = threadIdx.x, wave = tid >> 6, lane = tid & 63;
  const int p = blockIdx.x;
  const int rowg = p >> 6;                   // batch slab: rows rowg*32..+32 (both phases)
  // phase A
  const int an0 = (p & 63) * 32;             // 0..2016 over [z|r]
  const int agate = (an0 >= 1024) ? 1 : 0;
  const int anl = an0 & 1023;
  // phase B
  const int bn0 = (p & 63) * 16;             // 0..1008 over i
  const int msub = wave >> 1, nsub = wave & 1;

  // one-time LDS weight residency (normal cached loads; swizzled store)
  {
    const unsigned short* wa = wh + (size_t)agate * 1024 * 1024 + (size_t)anl * 1024;
    const unsigned short* wb = wh + (size_t)2 * 1024 * 1024 + (size_t)bn0 * 1024;
    for (int idx = tid; idx < 32 * 128; idx += 256) {
      int row = idx >> 7, cl = idx & 127;
      int cp = cl ^ (row & 7);
      *(short8*)&WA[row * 1024 + cp * 8] = *(const short8*)&wa[(size_t)row * 1024 + cl * 8];
    }
    for (int idx = tid; idx < 16 * 128; idx += 256) {
      int row = idx >> 7, cl = idx & 127;
      int cp = cl ^ (row & 7);
      *(short8*)&WB[row * 1024 + cp * 8] = *(const short8*)&wb[(size_t)row * 1024 + cl * 8];
    }
  }
  __syncthreads();

  // per-thread fixed epilogue coordinates
  const int n0A = nsub * 16 + ((lane >> 4) << 2);            // 4 consecutive n
  const int mA = msub * 16 + (lane & 15);
  const int browA = rowg * 32 + mA;
  const size_t aoff = (size_t)browA * 1024 + (size_t)(anl + n0A);
  const unsigned short* preX = agate ? preR : preZ;

  const int waveB = wave & 1;                                // clamped for addr calc
  const int mB = rowg * 32 + waveB * 16 + (lane & 15);
  const int n0B = bn0 + ((lane >> 4) << 2);
  const size_t boff = (size_t)mB * 1024 + (size_t)n0B;

  // staging coords: thread -> (row, 8 chunks of 16B)
  const int srow = tid >> 3;                                  // 0..31
  const int scol = tid & 7;

  unsigned iv = 0;
  u64 preA8 = *(const u64*)(preX + aoff);                     // t=0 prefetch (normal)

  for (int t = 0; t < T_; ++t) {
    // =================== PHASE A ===================
    // coherent prefetch of h_{t-1} fp32 (for r*h), overlapped with staging
    const size_t hoffp = (size_t)(t > 0 ? t - 1 : 0) * BL_;
    u64 hpa0 = 0, hpa1 = 0;
    if (agate) { hpa0 = cload64(out + hoffp + aoff); hpa1 = cload64(out + hoffp + aoff + 2); }

    floatx4 acc0 = (floatx4){0.f, 0.f, 0.f, 0.f};
    floatx4 acc1 = (floatx4){0.f, 0.f, 0.f, 0.f};
    const int hrow = msub * 16 + (lane & 15);
    const int wrowA = nsub * 16 + (lane & 15);
    const int hx = hrow & 7, wxr = wrowA & 7;

    for (int kh = 0; kh < 2; ++kh) {
      // stage 32 rows x 512 k of h (bf16) via coherent 8B loads
      {
        const unsigned short* src = hb + (size_t)(rowg * 32 + srow) * 1024 + kh * 512;
        u64 v[16];
#pragma unroll
        for (int it = 0; it < 8; ++it) {
          int cl = scol + it * 8;
          v[2 * it] = cload64(src + cl * 8);
          v[2 * it + 1] = cload64(src + cl * 8 + 4);
        }
#pragma unroll
        for (int it = 0; it < 8; ++it) {
          int cl = scol + it * 8;
          int cp = cl ^ (srow & 7);
          *(u64*)&Hs[srow * 512 + cp * 8] = v[2 * it];
          *(u64*)&Hs[srow * 512 + cp * 8 + 4] = v[2 * it + 1];
        }
      }
      __syncthreads();
#pragma unroll
      for (int ks = 0; ks < 16; ks += 2) {
        int ck0 = ks * 4 + (lane >> 4);
        int ck1 = (ks + 1) * 4 + (lane >> 4);
        short8 h0 = *(const short8*)&Hs[hrow * 512 + ((ck0 ^ hx) * 8)];
        short8 w0 = *(const short8*)&WA[wrowA * 1024 + (((kh * 64 + ck0) ^ wxr) * 8)];
        acc0 = __builtin_amdgcn_mfma_f32_16x16x32_bf16(w0, h0, acc0, 0, 0, 0);
        short8 h1 = *(const short8*)&Hs[hrow * 512 + ((ck1 ^ hx) * 8)];
        short8 w1 = *(const short8*)&WA[wrowA * 1024 + (((kh * 64 + ck1) ^ wxr) * 8)];
        acc1 = __builtin_amdgcn_mfma_f32_16x16x32_bf16(w1, h1, acc1, 0, 0, 0);
      }
      __syncthreads();
    }

    // epilogue A: C row=(lane>>4)*4+reg -> n (W was 1st operand), col=lane&15 -> m
    {
      floatx4 acc = acc0 + acc1;
      float2 hA0 = unpack2f(hpa0), hA1 = unpack2f(hpa1);
      float hp[4] = {hA0.x, hA0.y, hA1.x, hA1.y};
      if (!agate) {
        float s0 = sigmoidf_(acc[0] + h2f((ushort)(preA8 >> 0)));
        float s1 = sigmoidf_(acc[1] + h2f((ushort)(preA8 >> 16)));
        float s2 = sigmoidf_(acc[2] + h2f((ushort)(preA8 >> 32)));
        float s3 = sigmoidf_(acc[3] + h2f((ushort)(preA8 >> 48)));
        cstore64(zbuf + aoff, pack2f(s0, s1));
        cstore64(zbuf + aoff + 2, pack2f(s2, s3));
      } else {
        u64 o = 0;
#pragma unroll
        for (int r = 0; r < 4; ++r) {
          float s = sigmoidf_(acc[r] + h2f((ushort)(preA8 >> (16 * r))));
          float v = (t > 0) ? s * hp[r] : 0.f;
          o |= (u64)f2bf(v) << (16 * r);
        }
        cstore64(rh + aoff, o);
      }
    }

    __syncthreads();                 // drains vmcnt in all waves, orders stores < arrive
    ++iv;
    bar_arrive(ctr, p, iv);
    // prefetch parked pre_i (read-only, normal cached) during the wait
    float4 preI4 = *(const float4*)(out + (size_t)t * BL_ + boff);
    bar_wait(ctr, p, iv);

    // =================== PHASE B ===================
    // coherent prefetches: z (written in phase A this step), h_{t-1}
    u64 z0 = cload64(zbuf + boff), z1 = cload64(zbuf + boff + 2);
    u64 hb0 = 0, hb1 = 0;
    if (t > 0) { hb0 = cload64(out + (size_t)(t - 1) * BL_ + boff); hb1 = cload64(out + (size_t)(t - 1) * BL_ + boff + 2); }

    floatx4 accB0 = (floatx4){0.f, 0.f, 0.f, 0.f};
    floatx4 accB1 = (floatx4){0.f, 0.f, 0.f, 0.f};
    const int rrow = (wave & 1) * 16 + (lane & 15);
    const int wrowB = lane & 15;
    const int rx = rrow & 7, wxb = wrowB & 7;

    for (int kh = 0; kh < 2; ++kh) {
      {
        const unsigned short* src = rh + (size_t)(rowg * 32 + srow) * 1024 + kh * 512;
        u64 v[16];
#pragma unroll
        for (int it = 0; it < 8; ++it) {
          int cl = scol + it * 8;
          v[2 * it] = cload64(src + cl * 8);
          v[2 * it + 1] = cload64(src + cl * 8 + 4);
        }
#pragma unroll
        for (int it = 0; it < 8; ++it) {
          int cl = scol + it * 8;
          int cp = cl ^ (srow & 7);
          *(u64*)&Hs[srow * 512 + cp * 8] = v[2 * it];
          *(u64*)&Hs[srow * 512 + cp * 8 + 4] = v[2 * it + 1];
        }
      }
      __syncthreads();
      if ((wave >> 1) == kh) {
#pragma unroll
        for (int ks = 0; ks < 16; ks += 2) {
          int ck0 = ks * 4 + (lane >> 4);
          int ck1 = (ks + 1) * 4 + (lane >> 4);
          short8 a0 = *(const short8*)&Hs[rrow * 512 + ((ck0 ^ rx) * 8)];
          short8 w0 = *(const short8*)&WB[wrowB * 1024 + (((kh * 64 + ck0) ^ wxb) * 8)];
          accB0 = __builtin_amdgcn_mfma_f32_16x16x32_bf16(w0, a0, accB0, 0, 0, 0);
          short8 a1 = *(const short8*)&Hs[rrow * 512 + ((ck1 ^ rx) * 8)];
          short8 w1 = *(const short8*)&WB[wrowB * 1024 + (((kh * 64 + ck1) ^ wxb) * 8)];
          accB1 = __builtin_amdgcn_mfma_f32_16x16x32_bf16(w1, a1, accB1, 0, 0, 0);
        }
      }
      __syncthreads();
    }
    floatx4 accB = accB0 + accB1;
    if (wave >= 2) *(floatx4*)&red[(wave - 2) * 256 + lane * 4] = accB;
    __syncthreads();
    if (wave < 2) {
      floatx4 r4 = *(const floatx4*)&red[wave * 256 + lane * 4];
      accB = accB + r4;
      float2 zA = unpack2f(z0), zB2 = unpack2f(z1);
      float zv[4] = {zA.x, zA.y, zB2.x, zB2.y};
      float2 hA = unpack2f(hb0), hB2 = unpack2f(hb1);
      float hpv[4] = {hA.x, hA.y, hB2.x, hB2.y};
      float pi[4] = {preI4.x, preI4.y, preI4.z, preI4.w};
      float hn[4];
      u64 ob = 0;
#pragma unroll
      for (int r = 0; r < 4; ++r) {
        float ivl = tanhf_(accB[r] + pi[r]);
        float hprev = (t > 0) ? hpv[r] : 0.f;
        hn[r] = (1.f - zv[r]) * hprev + zv[r] * ivl;
        ob |= (u64)f2bf(hn[r]) << (16 * r);
      }
      cstore64(out + (size_t)t * BL_ + boff, pack2f(hn[0], hn[1]));
      cstore64(out + (size_t)t * BL_ + boff + 2, pack2f(hn[2], hn[3]));
      cstore64(hb + boff, ob);
    }

    if (t + 1 < T_) {
      __syncthreads();
      ++iv;
      bar_arrive(ctr, p, iv);
      // prefetch next step's pre-activation (read-only) during the wait
      int tn = t + 1;
      preA8 = *(const u64*)(preX + (size_t)tn * BL_ + aoff);
      bar_wait(ctr, p, iv);
    }
  }
}

extern "C" void kernel_launch(void* const* d_in, const int* in_sizes, int n_in,
                              void* d_out, int out_size, void* d_ws, size_t ws_size,
                              hipStream_t stream) {
  const float* x  = (const float*)d_in[0];
  const float* Wz = (const float*)d_in[1];
  const float* bz = (const float*)d_in[2];
  const float* Wr = (const float*)d_in[3];
  const float* br = (const float*)d_in[4];
  const float* Wi = (const float*)d_in[5];
  const float* bi = (const float*)d_in[6];
  float* out = (float*)d_out;
  char* wsb = (char*)d_ws;

  unsigned short* preZ = (unsigned short*)(wsb + OFF_PREZ);
  unsigned short* preR = (unsigned short*)(wsb + OFF_PRER);
  unsigned short* wh   = (unsigned short*)(wsb + OFF_WH);
  unsigned short* wx   = (unsigned short*)(wsb + OFF_WX);
  unsigned short* xb   = (unsigned short*)(wsb + OFF_XB);
  unsigned short* hb   = (unsigned short*)(wsb + OFF_HB);
  unsigned short* rh   = (unsigned short*)(wsb + OFF_RH);
  float* zbuf          = (float*)(wsb + OFF_Z);
  unsigned* ctr        = (unsigned*)(wsb + OFF_CTR);

  hipMemsetAsync(wsb + OFF_HB, 0, (size_t)B_ * L_ * 2, stream);   // h0 = 0
  hipMemsetAsync(wsb + OFF_CTR, 0, 16384, stream);                // barrier counters

  k_conv_x<<<8192, 256, 0, stream>>>(x, xb);
  k_conv_w<<<2304, 256, 0, stream>>>(Wz, Wr, Wi, wx, wh);
  k_pre_gemm<<<dim3(256, 24), 256, 0, stream>>>(xb, wx, preZ, preR, out, bz, br, bi);
  k_gru<<<256, 256, 0, stream>>>(wh, preZ, preR, hb, rh, zbuf, out, ctr);
}